// Round 5
// baseline (138.031 us; speedup 1.0000x reference)
//
#include <hip/hip_runtime.h>

#define BB 64
#define NN 512
#define FD 64

typedef short bf16x8 __attribute__((ext_vector_type(8)));
typedef float f32x4 __attribute__((ext_vector_type(4)));

__device__ __forceinline__ unsigned short f2bf(float f){
    unsigned u = __builtin_bit_cast(unsigned, f);
    u += 0x7fffu + ((u >> 16) & 1u);           // RNE
    return (unsigned short)(u >> 16);
}
__device__ __forceinline__ float bf2f(unsigned short h){
    unsigned u = ((unsigned)h) << 16;
    return __builtin_bit_cast(float, u);
}
__device__ __forceinline__ float fast_tanh(float x){
    float e = __expf(2.0f * x);                 // inf -> 1, 0 -> -1: saturates correctly
    return 1.0f - 2.0f * __builtin_amdgcn_rcpf(e + 1.0f);
}

// XW = X @ W via MFMA (W transposed in-block, k_prep folded in);
// emits XWh[b][n][f] (natural) and XWt[b][f][n] (transposed), bf16
__global__ __launch_bounds__(256) void k_xw(const float* __restrict__ X,
                                            const float* __restrict__ W,
                                            unsigned short* __restrict__ XWh,
                                            unsigned short* __restrict__ XWt){
    __shared__ unsigned short Xl[64][72];
    __shared__ unsigned short Wtl[64][72];
    __shared__ unsigned short Cl[64][72];    // C natural [n][f]
    __shared__ unsigned short ClT[64][72];   // C transposed [f][n]
    int t = threadIdx.x;
    int row0 = blockIdx.x * 64;
    int r = t >> 2, c0 = (t & 3) * 16;
    {   // W rows r (c-index), cols c0.. (d-index) -> scatter transpose to Wtl[d][c]
        const float4* wsrc = (const float4*)&W[r*64 + c0];
        #pragma unroll
        for (int q = 0; q < 4; q++){
            float4 v = wsrc[q];
            Wtl[c0 + q*4 + 0][r] = f2bf(v.x);
            Wtl[c0 + q*4 + 1][r] = f2bf(v.y);
            Wtl[c0 + q*4 + 2][r] = f2bf(v.z);
            Wtl[c0 + q*4 + 3][r] = f2bf(v.w);
        }
        const float4* src = (const float4*)&X[(row0 + r)*FD + c0];
        #pragma unroll
        for (int q = 0; q < 4; q++){
            float4 v = src[q];
            ushort4 h; h.x=f2bf(v.x); h.y=f2bf(v.y); h.z=f2bf(v.z); h.w=f2bf(v.w);
            *(ushort4*)&Xl[r][c0 + q*4] = h;
        }
    }
    __syncthreads();
    int lane = t & 63, w = t >> 6, l15 = lane & 15, quad = lane >> 4;
    f32x4 acc[4] = {{0,0,0,0},{0,0,0,0},{0,0,0,0},{0,0,0,0}};
    #pragma unroll
    for (int ks = 0; ks < 2; ks++){
        bf16x8 af = *(const bf16x8*)&Xl[w*16 + l15][ks*32 + quad*8];
        #pragma unroll
        for (int nt = 0; nt < 4; nt++){
            bf16x8 bfr = *(const bf16x8*)&Wtl[nt*16 + l15][ks*32 + quad*8];
            acc[nt] = __builtin_amdgcn_mfma_f32_16x16x32_bf16(af, bfr, acc[nt], 0, 0, 0);
        }
    }
    #pragma unroll
    for (int nt = 0; nt < 4; nt++)
        #pragma unroll
        for (int rg = 0; rg < 4; rg++){
            unsigned short hb = f2bf(acc[nt][rg]);
            Cl [w*16 + quad*4 + rg][nt*16 + l15] = hb;
            ClT[nt*16 + l15][w*16 + quad*4 + rg] = hb;
        }
    __syncthreads();
    int b = blockIdx.x >> 3, n0 = (blockIdx.x & 7) * 64;
    {   // natural: contiguous rows of Cl
        uint4 v0 = *(const uint4*)&Cl[r][c0];
        uint4 v1 = *(const uint4*)&Cl[r][c0 + 8];
        *(uint4*)&XWh[(row0 + r)*FD + c0]     = v0;
        *(uint4*)&XWh[(row0 + r)*FD + c0 + 8] = v1;
    }
    {   // transposed: contiguous rows of ClT -> 128B segments
        uint4 v0 = *(const uint4*)&ClT[r][c0];
        uint4 v1 = *(const uint4*)&ClT[r][c0 + 8];
        *(uint4*)&XWt[(b*64 + r)*NN + n0 + c0]     = v0;
        *(uint4*)&XWt[(b*64 + r)*NN + n0 + c0 + 8] = v1;
    }
}

// Fused per 32-row i-tile: M = (A_ @ XW) * diag(colsum) in LDS, then
// H = tanh(M @ XW^T + rowsum*bias_a) @ XW + bias_W  (flash over 8 j-chunks)
// 512 thr / 8 waves: wave w -> rows (w&1)*16, cols (w>>1)*16 (1 MFMA tile each)
__global__ __launch_bounds__(512, 8) void k_fused(const float* __restrict__ A,
                                                  const unsigned short* __restrict__ XWh,
                                                  const unsigned short* __restrict__ XWt,
                                                  const float* __restrict__ a,
                                                  const int* __restrict__ Ni,
                                                  const float* __restrict__ bias_a,
                                                  const float* __restrict__ bias_W,
                                                  float* __restrict__ H){
    __shared__ unsigned short s0[64][72];   // A chunk (32 rows used, phase A) / XWh chunk (phase B)
    __shared__ unsigned short s1[64][72];   // XWt chunk (both phases)
    __shared__ unsigned short MPl[32][72];  // M tile, reused as P tile
    __shared__ float cspart[8][64];
    __shared__ float csl[64];
    __shared__ float rspart[32][16];
    __shared__ float rsl[32];
    __shared__ float bl[512];
    int t = threadIdx.x;
    int b = blockIdx.y, it = blockIdx.x;
    int i0 = it * 32;
    int Nb = (Ni[1] == 0) ? Ni[2*b] : Ni[b];   // int64 vs int32 layout
    int lane = t & 63, w = t >> 6, l15 = lane & 15, quad = lane >> 4;
    int wr = w & 1, wc = w >> 1;
    int r16 = t >> 4, cA = (t & 15) * 4;       // A staging (32x64 fp32)
    int r8 = t >> 3, c8 = (t & 7) * 8;         // bf16 staging (64x64)
    const float* Ab = A + (b*NN + i0)*NN;
    const unsigned short* XWtb = XWt + b*64*NN;
    const unsigned short* XWhb = XWh + b*NN*FD;

    // colsum partials from a (overlaps phase A; needed only at M-write)
    {
        int cd = t & 63, cp = t >> 6;
        float s = 0.f;
        #pragma unroll
        for (int i = 0; i < 8; i++) s += a[(cp*8 + i)*64 + cd];
        cspart[cp][cd] = s;
    }
    bl[t] = bias_a[t];

    // ---- phase A: M tile + rowsum, pipelined over 8 k-chunks ----
    float4 pA = *(const float4*)&Ab[r16*NN + cA];
    uint4  pB = *(const uint4*)&XWtb[r8*NN + c8];
    f32x4 acc = {0,0,0,0};
    float rs = 0.f;
    int diagc = it >> 1;
    for (int c = 0; c < 8; c++){
        __syncthreads();
        {
            float4 v = pA;
            rs += v.x + v.y + v.z + v.w;
            ushort4 h; h.x=f2bf(v.x); h.y=f2bf(v.y); h.z=f2bf(v.z); h.w=f2bf(v.w);
            *(ushort4*)&s0[r16][cA] = h;
        }
        *(uint4*)&s1[r8][c8] = pB;
        __syncthreads();
        if (c < 7){   // prefetch next chunk while MFMAs run
            pA = *(const float4*)&Ab[r16*NN + (c+1)*64 + cA];
            pB = *(const uint4*)&XWtb[r8*NN + (c+1)*64 + c8];
        }
        #pragma unroll
        for (int ks = 0; ks < 2; ks++){
            bf16x8 af  = *(const bf16x8*)&s0[wr*16 + l15][ks*32 + quad*8];
            bf16x8 bfr = *(const bf16x8*)&s1[wc*16 + l15][ks*32 + quad*8];
            acc = __builtin_amdgcn_mfma_f32_16x16x32_bf16(af, bfr, acc, 0, 0, 0);
        }
        if (c == diagc){   // diagonal of A_: adds XW[i,:] for i < Nb
            #pragma unroll
            for (int rg = 0; rg < 4; rg++){
                int li = wr*16 + quad*4 + rg;
                if (i0 + li < Nb)
                    acc[rg] += bf2f(s1[wc*16 + l15][(it & 1)*32 + li]);
            }
        }
    }
    rspart[r16][t & 15] = rs;
    __syncthreads();
    if (t < 64){
        float s = 0.f;
        #pragma unroll
        for (int p = 0; p < 8; p++) s += cspart[p][t];
        csl[t] = s;
    } else if (t < 96){
        int row = t - 64;
        float s = 0.f;
        #pragma unroll
        for (int p = 0; p < 16; p++) s += rspart[row][p];
        if (i0 + row < Nb) s += 1.f;
        rsl[row] = s;
    }
    __syncthreads();
    // M = acc * colsum[col] into LDS (row-major, A-operand readable)
    {
        float cs = csl[wc*16 + l15];
        #pragma unroll
        for (int rg = 0; rg < 4; rg++)
            MPl[wr*16 + quad*4 + rg][wc*16 + l15] = f2bf(acc[rg] * cs);
    }
    __syncthreads();
    bf16x8 maf[2];   // GEMM1 A-frags chunk-invariant: hoist (MPl then free for P)
    maf[0] = *(const bf16x8*)&MPl[wr*16 + l15][quad*8];
    maf[1] = *(const bf16x8*)&MPl[wr*16 + l15][32 + quad*8];
    float rs_r[4];
    #pragma unroll
    for (int rg = 0; rg < 4; rg++) rs_r[rg] = rsl[wr*16 + quad*4 + rg];

    // ---- phase B: flash loop over 8 j-chunks, pipelined ----
    uint4 q1 = *(const uint4*)&XWhb[r8*FD + c8];
    uint4 q2 = *(const uint4*)&XWtb[r8*NN + c8];
    f32x4 hacc = {0,0,0,0};
    for (int jt = 0; jt < 8; jt++){
        __syncthreads();
        *(uint4*)&s0[r8][c8] = q1;
        *(uint4*)&s1[r8][c8] = q2;
        __syncthreads();
        if (jt < 7){
            q1 = *(const uint4*)&XWhb[((jt+1)*64 + r8)*FD + c8];
            q2 = *(const uint4*)&XWtb[r8*NN + (jt+1)*64 + c8];
        }
        {
            float bv = bl[jt*64 + wc*16 + l15];
            f32x4 arg = { rs_r[0]*bv, rs_r[1]*bv, rs_r[2]*bv, rs_r[3]*bv };
            #pragma unroll
            for (int ks = 0; ks < 2; ks++){
                bf16x8 bfr = *(const bf16x8*)&s0[wc*16 + l15][ks*32 + quad*8];
                arg = __builtin_amdgcn_mfma_f32_16x16x32_bf16(maf[ks], bfr, arg, 0, 0, 0);
            }
            #pragma unroll
            for (int rg = 0; rg < 4; rg++)
                MPl[wr*16 + quad*4 + rg][wc*16 + l15] = f2bf(fast_tanh(arg[rg]));
        }
        __syncthreads();
        #pragma unroll
        for (int ks = 0; ks < 2; ks++){
            bf16x8 paf = *(const bf16x8*)&MPl[wr*16 + l15][ks*32 + quad*8];
            bf16x8 bfr = *(const bf16x8*)&s1[wc*16 + l15][ks*32 + quad*8];
            hacc = __builtin_amdgcn_mfma_f32_16x16x32_bf16(paf, bfr, hacc, 0, 0, 0);
        }
    }
    {
        float bw = bias_W[wc*16 + l15];
        #pragma unroll
        for (int rg = 0; rg < 4; rg++)
            H[(b*NN + i0 + wr*16 + quad*4 + rg)*FD + wc*16 + l15] = hacc[rg] + bw;
    }
}

extern "C" void kernel_launch(void* const* d_in, const int* in_sizes, int n_in,
                              void* d_out, int out_size, void* d_ws, size_t ws_size,
                              hipStream_t stream){
    const float* X      = (const float*)d_in[0];
    const float* A      = (const float*)d_in[1];
    const int*   N      = (const int*)  d_in[2];
    const float* W      = (const float*)d_in[3];
    const float* a      = (const float*)d_in[4];
    const float* bias_W = (const float*)d_in[5];
    const float* bias_a = (const float*)d_in[6];
    float* H = (float*)d_out;
    char* ws = (char*)d_ws;

    unsigned short* XWh = (unsigned short*)(ws);              // 4 MB
    unsigned short* XWt = (unsigned short*)(ws + (4u<<20));   // 4 MB

    k_xw   <<<BB * NN / 64, 256, 0, stream>>>(X, W, XWh, XWt);
    k_fused<<<dim3(16, BB), 512, 0, stream>>>(A, XWh, XWt, a, N, bias_a, bias_W, H);
}